// Round 13
// baseline (4445.710 us; speedup 1.0000x reference)
//
#include <hip/hip_runtime.h>
#include <hip/hip_bf16.h>
#include <math.h>

#define BATCH 8
#define SEQ   1024
#define DM    768
#define NHEAD 12
#define KVH   4
#define HD    64
#define REP   3

// ======== naive QKV, jax layout: W[in,out] row-major, y = x @ W + b ==========
// Q stored [B,NHEAD,T,HD]; K/V stored [B,KVH,T,HD] (bf16 intermediates).
__global__ __launch_bounds__(256) void qkv_naive(
    const float* __restrict__ x,
    const float* __restrict__ qw, const float* __restrict__ qb,
    const float* __restrict__ kw, const float* __restrict__ kb,
    const float* __restrict__ vw, const float* __restrict__ vb,
    __hip_bfloat16* __restrict__ Q, __hip_bfloat16* __restrict__ K,
    __hip_bfloat16* __restrict__ V)
{
    const long long gid = (long long)blockIdx.x * 256 + threadIdx.x;
    if (gid >= (long long)8192 * 1280) return;
    const int m  = (int)(gid / 1280);
    const int nv = (int)(gid % 1280);

    const float* W; const float* bias; __hip_bfloat16* outp; int Nw, nl, Hcnt;
    if (nv < 768)       { W = qw; bias = qb; Nw = 768; nl = nv;        outp = Q; Hcnt = NHEAD; }
    else if (nv < 1024) { W = kw; bias = kb; Nw = 256; nl = nv - 768;  outp = K; Hcnt = KVH; }
    else                { W = vw; bias = vb; Nw = 256; nl = nv - 1024; outp = V; Hcnt = KVH; }

    float acc = 0.f;
    for (int k = 0; k < DM; k++)
        acc += x[(size_t)m * DM + k] * W[(size_t)k * Nw + nl];
    acc += bias[nl];

    const int b = m >> 10, t = m & 1023;
    const int head = nl >> 6, d = nl & 63;
    outp[(((size_t)(b * Hcnt + head)) * SEQ + t) * HD + d] = __float2bfloat16(acc);
}

// ======== naive RoPE, out-of-place, INTERLEAVED (file-faithful) variant ======
// xh[k] = x[(k&1)*32 + k/2]; rot[j] = j<32 ? -xh[j+32] : xh[j-32]
// => partner = (j&1)*32 + j/2 + (j<32 ? 16 : -16)
__global__ __launch_bounds__(256) void rope_naive(
    const __hip_bfloat16* __restrict__ in, __hip_bfloat16* __restrict__ outb,
    const int* __restrict__ pos, long long nrows)
{
    const long long gid = (long long)blockIdx.x * 256 + threadIdx.x;
    if (gid >= nrows * 64) return;
    const long long row = gid >> 6;
    const int j = (int)(gid & 63);
    const int t = (int)(row & (SEQ - 1));

    // pos dtype robustness (int32 established; detector is ~free)
    float p;
    if (pos[1] == 1)                              p = (float)pos[t];
    else if (((const float*)pos)[1] == 1.0f)      p = ((const float*)pos)[t];
    else                                          p = (float)pos[2 * t];

    const float inv = exp2f(-(float)(j & 31) * (13.287712379549449f / 32.0f));
    float sv, cv;
    sincosf(p * inv, &sv, &cv);
    const int partner = (j & 1) * 32 + (j >> 1) + ((j < 32) ? 16 : -16);
    const float sign  = (j < 32) ? -1.0f : 1.0f;
    const float val  = __bfloat162float(in[row * HD + j]);
    const float pv   = __bfloat162float(in[row * HD + partner]);
    outb[row * HD + j] = __float2bfloat16(val * cv + sign * pv * sv);
}

// ======== naive causal grouped attention, g = h / REP (file-faithful) ========
__global__ __launch_bounds__(64) void attn_naive(
    const __hip_bfloat16* __restrict__ Q, const __hip_bfloat16* __restrict__ K,
    const __hip_bfloat16* __restrict__ V, __hip_bfloat16* __restrict__ outp)
{
    const int bid = blockIdx.x;                 // b*(NHEAD*SEQ) + h*SEQ + t
    const int b   = bid / (NHEAD * SEQ);
    const int rem = bid % (NHEAD * SEQ);
    const int h   = rem / SEQ;
    const int t   = rem % SEQ;
    const int g   = h / REP;
    const int lane = threadIdx.x;               // 0..63

    const __hip_bfloat16* q  = Q + ((size_t)(b * NHEAD + h) * SEQ + t) * HD;
    const __hip_bfloat16* Kb = K + (size_t)(b * KVH + g) * SEQ * HD;
    const __hip_bfloat16* Vb = V + (size_t)(b * KVH + g) * SEQ * HD;

    __shared__ float p[SEQ];
    __shared__ float partial[64];
    __shared__ float qs[64];
    __shared__ float linv_s;

    qs[lane] = __bfloat162float(q[lane]);
    __syncthreads();

    float psum = 0.f;
    for (int s = lane; s <= t; s += 64) {
        float acc = 0.f;
        for (int d = 0; d < HD; d++)
            acc += qs[d] * __bfloat162float(Kb[(size_t)s * HD + d]);
        const float e = expf(acc * 0.125f);     // bounded -> finite
        p[s] = e;
        psum += e;
    }
    partial[lane] = psum;
    __syncthreads();
    if (lane == 0) {
        float l = 0.f;
        for (int i = 0; i < 64; i++) l += partial[i];
        linv_s = 1.0f / fmaxf(l, 1e-37f);
    }
    __syncthreads();
    const float linv = linv_s;

    float acc = 0.f;
    for (int s = 0; s <= t; s++)
        acc += p[s] * __bfloat162float(Vb[(size_t)s * HD + lane]);

    outp[((size_t)(b * SEQ + t)) * DM + h * HD + lane] = __float2bfloat16(acc * linv);
}

// ======== naive output projection, jax layout; FP32 FINAL STORE ==============
// attn[8192,768](bf16) @ ow[768,768](fp32, [in,out]) + ob -> out fp32
__global__ __launch_bounds__(256) void oproj_naive(
    const __hip_bfloat16* __restrict__ A, const float* __restrict__ W,
    const float* __restrict__ bias, float* __restrict__ outp)
{
    const long long gid = (long long)blockIdx.x * 256 + threadIdx.x;
    if (gid >= (long long)8192 * 768) return;
    const int m = (int)(gid / 768), n = (int)(gid % 768);
    float acc = 0.f;
    for (int k = 0; k < DM; k++)
        acc += __bfloat162float(A[(size_t)m * DM + k]) * W[(size_t)k * DM + n];
    outp[(size_t)m * DM + n] = acc + bias[n];   // <<< fp32 store (the fix)
}

extern "C" void kernel_launch(void* const* d_in, const int* in_sizes, int n_in,
                              void* d_out, int out_size, void* d_ws, size_t ws_size,
                              hipStream_t stream) {
    const float* x   = (const float*)d_in[0];
    const int*   pos = (const int*)d_in[1];
    const float* qw  = (const float*)d_in[2];
    const float* qb  = (const float*)d_in[3];
    const float* kw  = (const float*)d_in[4];
    const float* kb  = (const float*)d_in[5];
    const float* vw  = (const float*)d_in[6];
    const float* vb  = (const float*)d_in[7];
    const float* ow  = (const float*)d_in[8];
    const float* ob  = (const float*)d_in[9];
    float* out = (float*)d_out;                 // OUTPUT IS FP32

    // ws carve (bf16): Qbuf | Qrot | Kbuf | Krot | Vbuf = 36 MiB total
    __hip_bfloat16* Qbuf = (__hip_bfloat16*)d_ws;
    __hip_bfloat16* Qrot = Qbuf + (size_t)BATCH*NHEAD*SEQ*HD;
    __hip_bfloat16* Kbuf = Qrot + (size_t)BATCH*NHEAD*SEQ*HD;
    __hip_bfloat16* Krot = Kbuf + (size_t)BATCH*KVH*SEQ*HD;
    __hip_bfloat16* Vbuf = Krot + (size_t)BATCH*KVH*SEQ*HD;
    __hip_bfloat16* attn = Qbuf;   // reuse after rope consumes Qbuf

    const long long qkv_threads = (long long)8192 * 1280;
    qkv_naive<<<(int)((qkv_threads + 255) / 256), 256, 0, stream>>>(
        x, qw, qb, kw, kb, vw, vb, Qbuf, Kbuf, Vbuf);

    const long long qrows = (long long)BATCH * NHEAD * SEQ;   // 98304
    const long long krows = (long long)BATCH * KVH * SEQ;     // 32768
    rope_naive<<<(int)((qrows * 64 + 255) / 256), 256, 0, stream>>>(Qbuf, Qrot, pos, qrows);
    rope_naive<<<(int)((krows * 64 + 255) / 256), 256, 0, stream>>>(Kbuf, Krot, pos, krows);

    attn_naive<<<BATCH * NHEAD * SEQ, 64, 0, stream>>>(Qrot, Krot, Vbuf, attn);

    const long long o_threads = (long long)8192 * 768;
    oproj_naive<<<(int)((o_threads + 255) / 256), 256, 0, stream>>>(attn, ow, ob, out);
}